// Round 4
// baseline (573.572 us; speedup 1.0000x reference)
//
#include <hip/hip_runtime.h>
#include <math.h>

#define BB 32
#define SS 2048
#define HH 1024
#define MT (BB*SS)      // 65536 rows

#define BM 256
#define BN 256
#define BK 32           // fp32 k per tile (hi/lo bf16 -> 64 bf16-equivalent)
#define NT (HH/BK)      // 32 k-tiles
#define NCH (HH/BN)     // 4 n-chunks
#define THREADS 512

typedef float  f32x4 __attribute__((ext_vector_type(4)));
typedef short  s16x8 __attribute__((ext_vector_type(8)));
typedef unsigned short u16;

// truncation split: x ~= hi + lo, |x - hi - lo| <= 2^-16 |x|
__device__ inline void split1(float x, u16& h, u16& l) {
    unsigned u = __float_as_uint(x);
    h = (u16)(u >> 16);
    float hf = __uint_as_float((u >> 16) << 16);
    l = (u16)(__float_as_uint(x - hf) >> 16);
}
__device__ inline void split8v(float4 v0, float4 v1, s16x8& h, s16x8& l) {
    float x[8] = {v0.x,v0.y,v0.z,v0.w,v1.x,v1.y,v1.z,v1.w};
    #pragma unroll
    for (int j = 0; j < 8; ++j) {
        u16 hh, ll; split1(x[j], hh, ll);
        h[j] = (short)hh; l[j] = (short)ll;
    }
}

// ---------------- Kernel 1: dec_proj[b][n] = dh[b]·Wa_w[:,n] + Wa_b[n] + Ua_b[n]
__global__ void dec_proj_kernel(const float* __restrict__ dh,
                                const float* __restrict__ Wa_w,
                                const float* __restrict__ Wa_b,
                                const float* __restrict__ Ua_b,
                                float* __restrict__ dec_proj) {
    __shared__ float sdh[HH];
    const int b   = blockIdx.x;
    const int nq  = blockIdx.y;           // 0..3
    const int tid = threadIdx.x;          // 256
    for (int i = tid; i < HH; i += 256) sdh[i] = dh[b*HH + i];
    __syncthreads();
    const int n = nq*256 + tid;
    float acc = Wa_b[n] + Ua_b[n];
    for (int k = 0; k < HH; ++k)
        acc = fmaf(sdh[k], Wa_w[(size_t)k*HH + n], acc);
    dec_proj[b*HH + n] = acc;
}

// ---------------- Kernel 2: Ua [K][N] -> Bh_t/Bl_t [N][K] split-bf16
__global__ void transpose_convert_kernel(const float* __restrict__ Ua,
                                         u16* __restrict__ Bh_t,
                                         u16* __restrict__ Bl_t) {
    __shared__ u16 shh[64][72], shl[64][72];
    const int nb = blockIdx.x * 64, kb = blockIdx.y * 64;
    const int tid = threadIdx.x;          // 256
    const int kl = tid >> 4, nl4 = (tid & 15) * 4;
    #pragma unroll
    for (int q = 0; q < 4; ++q) {
        const int k = kl + q*16;
        float4 v = *(const float4*)&Ua[(size_t)(kb + k)*HH + nb + nl4];
        float x[4] = {v.x, v.y, v.z, v.w};
        #pragma unroll
        for (int j = 0; j < 4; ++j) {
            u16 hh, ll; split1(x[j], hh, ll);
            shh[k][nl4 + j] = hh; shl[k][nl4 + j] = ll;
        }
    }
    __syncthreads();
    const int nl = tid >> 3, kc8 = (tid & 7) * 8;
    #pragma unroll
    for (int q = 0; q < 2; ++q) {
        const int n = nl + q*32;
        s16x8 hv, lv;
        #pragma unroll
        for (int j = 0; j < 8; ++j) { hv[j] = (short)shh[kc8 + j][n]; lv[j] = (short)shl[kc8 + j][n]; }
        *(s16x8*)&Bh_t[(size_t)(nb + n)*HH + kb + kc8] = hv;
        *(s16x8*)&Bl_t[(size_t)(nb + n)*HH + kb + kc8] = lv;
    }
}

// ---------------- Kernel 3: 8-phase-style split-bf16 3-product MFMA GEMM
// 256x256 tile, 8 waves (2m x 4n), per-wave 128x64, dbuf LDS 128KB.
// Per K-tile: 4 phases {frag reads + 1 stage step, s_barrier, MFMA quad, s_barrier}.
// Raw barriers (no vmcnt drain) keep staged global loads in flight ~2 phases;
// one lgkmcnt(0) fence per tile orders ds_writes vs next tile's reads.
__global__ __launch_bounds__(THREADS, 1)
void gemm8_kernel(const float* __restrict__ A,        // enc [M, K] fp32
                  const u16* __restrict__ Bh_t,       // [N, K] bf16-hi
                  const u16* __restrict__ Bl_t,       // [N, K] bf16-lo
                  const float* __restrict__ dec_proj, // [B, H] (biases folded)
                  const float* __restrict__ Va_w,     // [H]
                  float* __restrict__ partials)       // [M, 16]
{
    __shared__ u16 AhS[2][BM*BK], AlS[2][BM*BK];
    __shared__ u16 BhS[2][BN*BK], BlS[2][BN*BK];

    // XCD mapping: mt fastest within an XCD, nch = epoch -> B L2-resident,
    // A one HBM pass + L3 re-reads across epochs.
    const int bid = blockIdx.x;
    const int xcd = bid & 7, idx = bid >> 3;
    const int nch = idx >> 5;                 // 0..3
    const int mt  = xcd*32 + (idx & 31);      // 0..255
    const int m0  = mt*BM, n0 = nch*BN;

    const int tid  = threadIdx.x;
    const int lane = tid & 63, wid = tid >> 6;
    const int wm   = wid >> 2, wn = wid & 3;  // 2 x 4 waves
    const int lr   = lane & 15, lk = lane >> 4;

    // ---- staging decomposition: thread t -> row t>>1, k-half t&1
    const int srow = tid >> 1, shalf = tid & 1;
    const float* Abase  = A    + (size_t)(m0 + srow)*HH + shalf*16;
    const u16*   Bhbase = Bh_t + (size_t)(n0 + srow)*HH + shalf*16;
    const u16*   Blbase = Bl_t + (size_t)(n0 + srow)*HH + shalf*16;
    const int c0 = shalf*2;
    // swizzled LDS offsets (u16 units): off(r,c) = r*32 + ((c ^ (r&3))<<3)
    const int woff0 = srow*BK + (((c0  ) ^ (srow&3)) << 3);
    const int woff1 = srow*BK + (((c0+1) ^ (srow&3)) << 3);
    // frag read k-chunk: c' = lk ^ (row&3) = lk ^ (lr&3) (row = 16*f + lr)
    const int ox = ((lk ^ (lr&3)) << 3);

    f32x4 acc[8][4];
    #pragma unroll
    for (int i = 0; i < 8; ++i)
        #pragma unroll
        for (int j = 0; j < 4; ++j) acc[i][j] = (f32x4){0.f,0.f,0.f,0.f};

    float4 a_r[4];
    s16x8  b_r[4];
    s16x8  ah[4], al[4];   // A frags persist across the 2 n-quadrant phases
    s16x8  bh[2], bl[2];

    auto load_A = [&](int kt) {
        const float* p = Abase + kt*BK;
        a_r[0] = *(const float4*)(p + 0);
        a_r[1] = *(const float4*)(p + 4);
        a_r[2] = *(const float4*)(p + 8);
        a_r[3] = *(const float4*)(p + 12);
    };
    auto load_B = [&](int kt) {
        b_r[0] = *(const s16x8*)(Bhbase + kt*BK);
        b_r[1] = *(const s16x8*)(Bhbase + kt*BK + 8);
        b_r[2] = *(const s16x8*)(Blbase + kt*BK);
        b_r[3] = *(const s16x8*)(Blbase + kt*BK + 8);
    };
    auto write_A = [&](int wb) {
        s16x8 h, l;
        split8v(a_r[0], a_r[1], h, l);
        *(s16x8*)&AhS[wb][woff0] = h; *(s16x8*)&AlS[wb][woff0] = l;
        split8v(a_r[2], a_r[3], h, l);
        *(s16x8*)&AhS[wb][woff1] = h; *(s16x8*)&AlS[wb][woff1] = l;
    };
    auto write_B = [&](int wb) {
        *(s16x8*)&BhS[wb][woff0] = b_r[0];
        *(s16x8*)&BhS[wb][woff1] = b_r[1];
        *(s16x8*)&BlS[wb][woff0] = b_r[2];
        *(s16x8*)&BlS[wb][woff1] = b_r[3];
    };
    auto read_A = [&](int cb, int qi) {
        #pragma unroll
        for (int ii = 0; ii < 4; ++ii) {
            const int r = wm*128 + (qi*4 + ii)*16 + lr;
            const int o = r*BK + ox;
            ah[ii] = *(const s16x8*)&AhS[cb][o];
            al[ii] = *(const s16x8*)&AlS[cb][o];
        }
    };
    auto read_B = [&](int cb, int qj) {
        #pragma unroll
        for (int jj = 0; jj < 2; ++jj) {
            const int r = wn*64 + (qj*2 + jj)*16 + lr;
            const int o = r*BK + ox;
            bh[jj] = *(const s16x8*)&BhS[cb][o];
            bl[jj] = *(const s16x8*)&BlS[cb][o];
        }
    };
    auto mfma_quad = [&](int qi, int qj) {
        __builtin_amdgcn_s_setprio(1);
        #pragma unroll
        for (int ii = 0; ii < 4; ++ii)
            #pragma unroll
            for (int jj = 0; jj < 2; ++jj) {
                f32x4 c = acc[qi*4 + ii][qj*2 + jj];
                c = __builtin_amdgcn_mfma_f32_16x16x32_bf16(ah[ii], bh[jj], c, 0, 0, 0);
                c = __builtin_amdgcn_mfma_f32_16x16x32_bf16(ah[ii], bl[jj], c, 0, 0, 0);
                c = __builtin_amdgcn_mfma_f32_16x16x32_bf16(al[ii], bh[jj], c, 0, 0, 0);
                acc[qi*4 + ii][qj*2 + jj] = c;
            }
        __builtin_amdgcn_s_setprio(0);
    };

    // prologue: tile 0 staged with a full barrier
    load_A(0); load_B(0);
    write_A(0); write_B(0);
    __syncthreads();

    for (int kt = 0; kt < NT; ++kt) {
        const int  cb = kt & 1;
        const bool hn = (kt + 1 < NT);
        // phase 0: issue A global loads for kt+1
        if (hn) load_A(kt + 1);
        read_A(cb, 0); read_B(cb, 0);
        __builtin_amdgcn_s_barrier();
        mfma_quad(0, 0);
        __builtin_amdgcn_s_barrier();
        // phase 1: issue B global loads for kt+1
        if (hn) load_B(kt + 1);
        read_B(cb, 1);
        __builtin_amdgcn_s_barrier();
        mfma_quad(0, 1);
        __builtin_amdgcn_s_barrier();
        // phase 2: split+write A (compiler inserts counted vmcnt wait)
        if (hn) write_A(cb ^ 1);
        read_A(cb, 1); read_B(cb, 0);
        __builtin_amdgcn_s_barrier();
        mfma_quad(1, 0);
        __builtin_amdgcn_s_barrier();
        // phase 3: write B; end-of-tile fence orders ds_writes vs next reads
        if (hn) write_B(cb ^ 1);
        read_B(cb, 1);
        __builtin_amdgcn_s_barrier();
        mfma_quad(1, 1);
        asm volatile("s_waitcnt lgkmcnt(0)" ::: "memory");
        __builtin_amdgcn_sched_barrier(0);
        __builtin_amdgcn_s_barrier();
    }

    // epilogue: rowsum over this block's 256 n-cols of Va[n]*tanh(C+dp[n])
    const int bidx = m0 >> 11;            // batch index (2048 rows per batch)
    float dp[4], va[4];
    #pragma unroll
    for (int j = 0; j < 4; ++j) {
        const int n = n0 + wn*64 + j*16 + lr;
        dp[j] = dec_proj[bidx*HH + n];
        va[j] = Va_w[n];
    }
    #pragma unroll
    for (int i = 0; i < 8; ++i) {
        #pragma unroll
        for (int r = 0; r < 4; ++r) {
            float s = 0.f;
            #pragma unroll
            for (int j = 0; j < 4; ++j)
                s += va[j] * tanhf(acc[i][j][r] + dp[j]);
            s += __shfl_xor(s, 1, 64);
            s += __shfl_xor(s, 2, 64);
            s += __shfl_xor(s, 4, 64);
            s += __shfl_xor(s, 8, 64);
            if (lr == 0) {
                const int m = m0 + wm*128 + i*16 + lk*4 + r;
                partials[(size_t)m*16 + nch*4 + wn] = s;
            }
        }
    }
}

// ---------------- Kernel 4: sum 16 partials + Va_b, mask, softmax over S
__global__ void softmax_kernel(const float* __restrict__ partials,
                               const int* __restrict__ mask,
                               const float* __restrict__ vb_ptr,
                               float* __restrict__ out)
{
    const int b   = blockIdx.x;
    const int tid = threadIdx.x;   // 256, each handles 8 s-positions
    __shared__ float sred[8];
    const float vb = vb_ptr[0];
    float sc[8];
    float mymax = -INFINITY;
    #pragma unroll
    for (int i = 0; i < 8; ++i) {
        const int s = i*256 + tid;
        const float4* p = (const float4*)&partials[((size_t)b*SS + s)*16];
        const float4 x = p[0], y = p[1], z = p[2], w = p[3];
        float v = (((x.x+x.y)+(x.z+x.w)) + ((y.x+y.y)+(y.z+y.w)))
                + (((z.x+z.y)+(z.z+z.w)) + ((w.x+w.y)+(w.z+w.w))) + vb;
        if (mask[b*SS + s] == 0) v = -1e9f;
        sc[i] = v;
        mymax = fmaxf(mymax, v);
    }
    #pragma unroll
    for (int off = 1; off < 64; off <<= 1)
        mymax = fmaxf(mymax, __shfl_xor(mymax, off, 64));
    const int wave = tid >> 6, lane = tid & 63;
    if (lane == 0) sred[wave] = mymax;
    __syncthreads();
    const float bmax = fmaxf(fmaxf(sred[0], sred[1]), fmaxf(sred[2], sred[3]));
    float ex[8], mysum = 0.f;
    #pragma unroll
    for (int i = 0; i < 8; ++i) {
        ex[i] = __expf(sc[i] - bmax);
        mysum += ex[i];
    }
    #pragma unroll
    for (int off = 1; off < 64; off <<= 1)
        mysum += __shfl_xor(mysum, off, 64);
    if (lane == 0) sred[4 + wave] = mysum;
    __syncthreads();
    const float inv = 1.f / (sred[4] + sred[5] + sred[6] + sred[7]);
    #pragma unroll
    for (int i = 0; i < 8; ++i)
        out[(size_t)b*SS + i*256 + tid] = ex[i] * inv;
}

extern "C" void kernel_launch(void* const* d_in, const int* in_sizes, int n_in,
                              void* d_out, int out_size, void* d_ws, size_t ws_size,
                              hipStream_t stream) {
    const float* dh   = (const float*)d_in[0];
    const float* enc  = (const float*)d_in[1];
    const int*   mask = (const int*)d_in[2];
    const float* Wa_w = (const float*)d_in[3];
    const float* Wa_b = (const float*)d_in[4];
    const float* Ua_w = (const float*)d_in[5];
    const float* Ua_b = (const float*)d_in[6];
    const float* Va_w = (const float*)d_in[7];
    const float* Va_b = (const float*)d_in[8];
    float* out = (float*)d_out;

    float* dec_proj = (float*)d_ws;                       // [B,H]    128 KB
    float* partials = dec_proj + BB*HH;                   // [M,16]   4 MB
    u16*   Bh_t     = (u16*)(partials + (size_t)MT*16);   // [N,K]    2 MB
    u16*   Bl_t     = Bh_t + (size_t)HH*HH;               // [N,K]    2 MB

    dec_proj_kernel<<<dim3(BB, 4), 256, 0, stream>>>(dh, Wa_w, Wa_b, Ua_b, dec_proj);
    transpose_convert_kernel<<<dim3(HH/64, HH/64), 256, 0, stream>>>(Ua_w, Bh_t, Bl_t);
    gemm8_kernel<<<(MT/BM)*NCH, THREADS, 0, stream>>>(enc, Bh_t, Bl_t, dec_proj, Va_w, partials);
    softmax_kernel<<<BB, 256, 0, stream>>>(partials, mask, Va_b, out);
}

// Round 5
// 469.191 us; speedup vs baseline: 1.2225x; 1.2225x over previous
//
#include <hip/hip_runtime.h>
#include <math.h>

#define BB 32
#define SS 2048
#define HH 1024
#define MT (BB*SS)      // 65536 rows

#define BM 256
#define BN 256
#define BK 32           // fp32 k per tile (hi/lo bf16 -> 64 bf16-equivalent)
#define NT (HH/BK)      // 32 k-tiles
#define NCH (HH/BN)     // 4 n-chunks
#define THREADS 512
// B_pre per (nch,kt) tile: 2 planes x 16 frags x 512 u16 = 16384 u16 (32KB)
#define BTILE 16384

typedef float  f32x4 __attribute__((ext_vector_type(4)));
typedef short  s16x8 __attribute__((ext_vector_type(8)));
typedef unsigned short u16;

// truncation split: x ~= hi + lo, |x - hi - lo| <= 2^-16 |x|
__device__ inline void split1(float x, u16& h, u16& l) {
    unsigned u = __float_as_uint(x);
    h = (u16)(u >> 16);
    float hf = __uint_as_float((u >> 16) << 16);
    l = (u16)(__float_as_uint(x - hf) >> 16);
}
__device__ inline void split8v(float4 v0, float4 v1, s16x8& h, s16x8& l) {
    float x[8] = {v0.x,v0.y,v0.z,v0.w,v1.x,v1.y,v1.z,v1.w};
    #pragma unroll
    for (int j = 0; j < 8; ++j) {
        u16 hh, ll; split1(x[j], hh, ll);
        h[j] = (short)hh; l[j] = (short)ll;
    }
}

// ---------------- Kernel 1: dec_proj[b][n] = dh[b]·Wa_w[:,n] + Wa_b[n] + Ua_b[n]
__global__ void dec_proj_kernel(const float* __restrict__ dh,
                                const float* __restrict__ Wa_w,
                                const float* __restrict__ Wa_b,
                                const float* __restrict__ Ua_b,
                                float* __restrict__ dec_proj) {
    __shared__ float sdh[HH];
    const int b   = blockIdx.x;
    const int nq  = blockIdx.y;           // 0..3
    const int tid = threadIdx.x;          // 256
    for (int i = tid; i < HH; i += 256) sdh[i] = dh[b*HH + i];
    __syncthreads();
    const int n = nq*256 + tid;
    float acc = Wa_b[n] + Ua_b[n];
    for (int k = 0; k < HH; ++k)
        acc = fmaf(sdh[k], Wa_w[(size_t)k*HH + n], acc);
    dec_proj[b*HH + n] = acc;
}

// ---------------- Kernel 2: Ua [K][N] -> B_pre frag-linear split-bf16 image
// B_pre[(nch*32+kt)*16384 + plane*8192 + f*512 + (c*16+lr)*8 + j]
//   n = nch*256 + f*16 + lr ; k = kt*32 + c*8 + j ; plane 0=hi,1=lo
__global__ void transpose_convert_kernel(const float* __restrict__ Ua,
                                         u16* __restrict__ B_pre) {
    __shared__ u16 shh[64][72], shl[64][72];
    const int nb = blockIdx.x * 64, kb = blockIdx.y * 64;
    const int tid = threadIdx.x;          // 256
    const int kl = tid >> 4, nl4 = (tid & 15) * 4;
    #pragma unroll
    for (int q = 0; q < 4; ++q) {
        const int k = kl + q*16;
        float4 v = *(const float4*)&Ua[(size_t)(kb + k)*HH + nb + nl4];
        float x[4] = {v.x, v.y, v.z, v.w};
        #pragma unroll
        for (int j = 0; j < 4; ++j) {
            u16 hh, ll; split1(x[j], hh, ll);
            shh[k][nl4 + j] = hh; shl[k][nl4 + j] = ll;
        }
    }
    __syncthreads();
    const int nl = tid >> 3, kc8 = (tid & 7) * 8;
    #pragma unroll
    for (int q = 0; q < 2; ++q) {
        const int n = nb + nl + q*32;
        const int kglob = kb + kc8;
        s16x8 hv, lv;
        #pragma unroll
        for (int j = 0; j < 8; ++j) {
            hv[j] = (short)shh[kc8 + j][nl + q*32];
            lv[j] = (short)shl[kc8 + j][nl + q*32];
        }
        const int nchI = n >> 8, fI = (n >> 4) & 15, lrI = n & 15;
        const int ktI = kglob >> 5, cI = (kglob >> 3) & 3;
        const size_t base = (size_t)(nchI*32 + ktI) * BTILE;
        const size_t idxH = base + fI*512 + (cI*16 + lrI)*8;
        *(s16x8*)&B_pre[idxH]        = hv;
        *(s16x8*)&B_pre[idxH + 8192] = lv;
    }
}

// ---------------- Kernel 3: frag-linear split-bf16 3-product MFMA GEMM
// 256x256 tile, 8 waves (2m x 4n), per-wave 128x64. LDS in exact MFMA frag
// order -> every frag ds_read_b128 is a contiguous 1024B wave read (0-conflict).
// B frags held per tile (read once); 4 phases over m-quads; raw barriers;
// single vmcnt/lgkm drain per tile with all vmem issued >=2 phases earlier.
__global__ __launch_bounds__(THREADS, 1)
void gemm8_kernel(const float* __restrict__ A,        // enc [M, K] fp32
                  const u16* __restrict__ B_pre,      // frag-linear split image
                  const float* __restrict__ dec_proj, // [B, H] (biases folded)
                  const float* __restrict__ Va_w,     // [H]
                  float* __restrict__ partials)       // [M, 16]
{
    __shared__ __align__(16) u16 AhS[2][BM*BK];
    __shared__ __align__(16) u16 AlS[2][BM*BK];
    __shared__ __align__(16) u16 BhS[2][BN*BK];
    __shared__ __align__(16) u16 BlS[2][BN*BK];

    // XCD-chunked bijective swizzle: 1024 blocks, 128 per XCD
    const int bid = blockIdx.x;
    const int wg  = (bid & 7) * 128 + (bid >> 3);
    const int nch = wg & 3;
    const int mt  = wg >> 2;
    const int m0  = mt * BM, n0 = nch * BN;

    const int tid = threadIdx.x, lane = tid & 63, wid = tid >> 6;
    const int wm = wid >> 2, wn = wid & 3;    // 2 x 4 waves
    const int lr = lane & 15, lk = lane >> 4;

    // A staging: thread -> row=tid>>1 (0..255), k-half=tid&1
    const int srow = tid >> 1, shalf = tid & 1;
    const float* Ab = A + (size_t)(m0 + srow)*HH + shalf*16;
    const int awoff0 = (srow>>4)*512 + (shalf*2    )*128 + (srow&15)*8;
    const int awoff1 = (srow>>4)*512 + (shalf*2 + 1)*128 + (srow&15)*8;
    // B staging: thread copies 4 x 16B, quarters of the 32KB tile image
    const u16* Bt = B_pre + (size_t)nch*32*BTILE + tid*8;

    f32x4 acc[8][4];
    #pragma unroll
    for (int i = 0; i < 8; ++i)
        #pragma unroll
        for (int j = 0; j < 4; ++j) acc[i][j] = (f32x4){0.f,0.f,0.f,0.f};

    s16x8 bh[4], bl[4];                 // held B frags (per tile)
    float4 a0_, a1_, a2_, a3_;          // A staging regs
    s16x8 bq0_, bq1_, bq2_, bq3_;       // B staging regs

    auto loadA0  = [&](int kt) { const float* p = Ab + kt*BK;
                                 a0_ = *(const float4*)p; a1_ = *(const float4*)(p+4); };
    auto loadA1  = [&](int kt) { const float* p = Ab + kt*BK + 8;
                                 a2_ = *(const float4*)p; a3_ = *(const float4*)(p+4); };
    auto loadB01 = [&](int kt) { const u16* p = Bt + (size_t)kt*BTILE;
                                 bq0_ = *(const s16x8*)p; bq1_ = *(const s16x8*)(p+4096); };
    auto loadB23 = [&](int kt) { const u16* p = Bt + (size_t)kt*BTILE;
                                 bq2_ = *(const s16x8*)(p+8192); bq3_ = *(const s16x8*)(p+12288); };
    auto writeA0 = [&](int b) { s16x8 h,l; split8v(a0_, a1_, h, l);
                                *(s16x8*)&AhS[b][awoff0] = h; *(s16x8*)&AlS[b][awoff0] = l; };
    auto writeA1 = [&](int b) { s16x8 h,l; split8v(a2_, a3_, h, l);
                                *(s16x8*)&AhS[b][awoff1] = h; *(s16x8*)&AlS[b][awoff1] = l; };
    auto writeB  = [&](int b) { *(s16x8*)&BhS[b][tid*8]        = bq0_;
                                *(s16x8*)&BhS[b][4096 + tid*8] = bq1_;
                                *(s16x8*)&BlS[b][tid*8]        = bq2_;
                                *(s16x8*)&BlS[b][4096 + tid*8] = bq3_; };
    auto readB = [&](int cb) {
        #pragma unroll
        for (int j = 0; j < 4; ++j) {
            const int off = (wn*4 + j)*512 + lane*8;   // contiguous 1KB per frag
            bh[j] = *(const s16x8*)&BhS[cb][off];
            bl[j] = *(const s16x8*)&BlS[cb][off];
        }
    };

    for (int kt = 0; kt < NT; ++kt) {
        const int  cb = kt & 1;
        const bool hn = (kt + 1 < NT);
        if (kt == 0) {   // prologue: stage tile 0 with full drain
            loadA0(0); loadA1(0); loadB01(0); loadB23(0);
            writeA0(0); writeA1(0); writeB(0);
            __syncthreads();
        }
        s16x8 ah[2], al[2];
        // ---- P0: issue A-half0 + B-q01 loads for kt+1; read held B + A-quad0
        if (hn) { loadA0(kt+1); loadB01(kt+1); }
        readB(cb);
        {   const int o0 = (wm*8 + 0)*512 + lane*8, o1 = (wm*8 + 1)*512 + lane*8;
            ah[0] = *(const s16x8*)&AhS[cb][o0]; al[0] = *(const s16x8*)&AlS[cb][o0];
            ah[1] = *(const s16x8*)&AhS[cb][o1]; al[1] = *(const s16x8*)&AlS[cb][o1]; }
        __builtin_amdgcn_s_barrier();
        __builtin_amdgcn_s_setprio(1);
        #pragma unroll
        for (int i = 0; i < 2; ++i)
            #pragma unroll
            for (int j = 0; j < 4; ++j) {
                f32x4 c = acc[i][j];
                c = __builtin_amdgcn_mfma_f32_16x16x32_bf16(ah[i], bh[j], c, 0, 0, 0);
                c = __builtin_amdgcn_mfma_f32_16x16x32_bf16(ah[i], bl[j], c, 0, 0, 0);
                c = __builtin_amdgcn_mfma_f32_16x16x32_bf16(al[i], bh[j], c, 0, 0, 0);
                acc[i][j] = c;
            }
        __builtin_amdgcn_s_setprio(0);
        __builtin_amdgcn_s_barrier();
        // ---- P1: issue A-half1 + B-q23 loads; read A-quad1
        if (hn) { loadA1(kt+1); loadB23(kt+1); }
        {   const int o0 = (wm*8 + 2)*512 + lane*8, o1 = (wm*8 + 3)*512 + lane*8;
            ah[0] = *(const s16x8*)&AhS[cb][o0]; al[0] = *(const s16x8*)&AlS[cb][o0];
            ah[1] = *(const s16x8*)&AhS[cb][o1]; al[1] = *(const s16x8*)&AlS[cb][o1]; }
        __builtin_amdgcn_s_barrier();
        __builtin_amdgcn_s_setprio(1);
        #pragma unroll
        for (int i = 0; i < 2; ++i)
            #pragma unroll
            for (int j = 0; j < 4; ++j) {
                f32x4 c = acc[2+i][j];
                c = __builtin_amdgcn_mfma_f32_16x16x32_bf16(ah[i], bh[j], c, 0, 0, 0);
                c = __builtin_amdgcn_mfma_f32_16x16x32_bf16(ah[i], bl[j], c, 0, 0, 0);
                c = __builtin_amdgcn_mfma_f32_16x16x32_bf16(al[i], bh[j], c, 0, 0, 0);
                acc[2+i][j] = c;
            }
        __builtin_amdgcn_s_setprio(0);
        __builtin_amdgcn_s_barrier();
        // ---- P2: split+write A-half0 into cb^1; read A-quad2
        if (hn) writeA0(cb ^ 1);
        {   const int o0 = (wm*8 + 4)*512 + lane*8, o1 = (wm*8 + 5)*512 + lane*8;
            ah[0] = *(const s16x8*)&AhS[cb][o0]; al[0] = *(const s16x8*)&AlS[cb][o0];
            ah[1] = *(const s16x8*)&AhS[cb][o1]; al[1] = *(const s16x8*)&AlS[cb][o1]; }
        __builtin_amdgcn_s_barrier();
        __builtin_amdgcn_s_setprio(1);
        #pragma unroll
        for (int i = 0; i < 2; ++i)
            #pragma unroll
            for (int j = 0; j < 4; ++j) {
                f32x4 c = acc[4+i][j];
                c = __builtin_amdgcn_mfma_f32_16x16x32_bf16(ah[i], bh[j], c, 0, 0, 0);
                c = __builtin_amdgcn_mfma_f32_16x16x32_bf16(ah[i], bl[j], c, 0, 0, 0);
                c = __builtin_amdgcn_mfma_f32_16x16x32_bf16(al[i], bh[j], c, 0, 0, 0);
                acc[4+i][j] = c;
            }
        __builtin_amdgcn_s_setprio(0);
        __builtin_amdgcn_s_barrier();
        // ---- P3: split+write A-half1 + B into cb^1; read A-quad3
        if (hn) { writeA1(cb ^ 1); writeB(cb ^ 1); }
        {   const int o0 = (wm*8 + 6)*512 + lane*8, o1 = (wm*8 + 7)*512 + lane*8;
            ah[0] = *(const s16x8*)&AhS[cb][o0]; al[0] = *(const s16x8*)&AlS[cb][o0];
            ah[1] = *(const s16x8*)&AhS[cb][o1]; al[1] = *(const s16x8*)&AlS[cb][o1]; }
        __builtin_amdgcn_s_barrier();
        __builtin_amdgcn_s_setprio(1);
        #pragma unroll
        for (int i = 0; i < 2; ++i)
            #pragma unroll
            for (int j = 0; j < 4; ++j) {
                f32x4 c = acc[6+i][j];
                c = __builtin_amdgcn_mfma_f32_16x16x32_bf16(ah[i], bh[j], c, 0, 0, 0);
                c = __builtin_amdgcn_mfma_f32_16x16x32_bf16(ah[i], bl[j], c, 0, 0, 0);
                c = __builtin_amdgcn_mfma_f32_16x16x32_bf16(al[i], bh[j], c, 0, 0, 0);
                acc[6+i][j] = c;
            }
        __builtin_amdgcn_s_setprio(0);
        // end-of-tile drain: all staged vmem issued >=2 phases ago
        asm volatile("s_waitcnt vmcnt(0) lgkmcnt(0)" ::: "memory");
        __builtin_amdgcn_sched_barrier(0);
        __builtin_amdgcn_s_barrier();
    }

    // epilogue: rowsum over this wave's 64 n-cols of Va[n]*tanh(C+dp[n])
    const int bidx = m0 >> 11;            // batch index (2048 rows per batch)
    float dp[4], va[4];
    #pragma unroll
    for (int j = 0; j < 4; ++j) {
        const int n = n0 + wn*64 + j*16 + lr;
        dp[j] = dec_proj[bidx*HH + n];
        va[j] = Va_w[n];
    }
    #pragma unroll
    for (int i = 0; i < 8; ++i) {
        #pragma unroll
        for (int r = 0; r < 4; ++r) {
            float s = 0.f;
            #pragma unroll
            for (int j = 0; j < 4; ++j)
                s += va[j] * tanhf(acc[i][j][r] + dp[j]);
            s += __shfl_xor(s, 1, 64);
            s += __shfl_xor(s, 2, 64);
            s += __shfl_xor(s, 4, 64);
            s += __shfl_xor(s, 8, 64);
            if (lr == 0) {
                const int m = m0 + wm*128 + i*16 + lk*4 + r;
                partials[(size_t)m*16 + nch*4 + wn] = s;
            }
        }
    }
}

// ---------------- Kernel 4: sum 16 partials + Va_b, mask, softmax over S
__global__ void softmax_kernel(const float* __restrict__ partials,
                               const int* __restrict__ mask,
                               const float* __restrict__ vb_ptr,
                               float* __restrict__ out)
{
    const int b   = blockIdx.x;
    const int tid = threadIdx.x;   // 256, each handles 8 s-positions
    __shared__ float sred[8];
    const float vb = vb_ptr[0];
    float sc[8];
    float mymax = -INFINITY;
    #pragma unroll
    for (int i = 0; i < 8; ++i) {
        const int s = i*256 + tid;
        const float4* p = (const float4*)&partials[((size_t)b*SS + s)*16];
        const float4 x = p[0], y = p[1], z = p[2], w = p[3];
        float v = (((x.x+x.y)+(x.z+x.w)) + ((y.x+y.y)+(y.z+y.w)))
                + (((z.x+z.y)+(z.z+z.w)) + ((w.x+w.y)+(w.z+w.w))) + vb;
        if (mask[b*SS + s] == 0) v = -1e9f;
        sc[i] = v;
        mymax = fmaxf(mymax, v);
    }
    #pragma unroll
    for (int off = 1; off < 64; off <<= 1)
        mymax = fmaxf(mymax, __shfl_xor(mymax, off, 64));
    const int wave = tid >> 6, lane = tid & 63;
    if (lane == 0) sred[wave] = mymax;
    __syncthreads();
    const float bmax = fmaxf(fmaxf(sred[0], sred[1]), fmaxf(sred[2], sred[3]));
    float ex[8], mysum = 0.f;
    #pragma unroll
    for (int i = 0; i < 8; ++i) {
        ex[i] = __expf(sc[i] - bmax);
        mysum += ex[i];
    }
    #pragma unroll
    for (int off = 1; off < 64; off <<= 1)
        mysum += __shfl_xor(mysum, off, 64);
    if (lane == 0) sred[4 + wave] = mysum;
    __syncthreads();
    const float inv = 1.f / (sred[4] + sred[5] + sred[6] + sred[7]);
    #pragma unroll
    for (int i = 0; i < 8; ++i)
        out[(size_t)b*SS + i*256 + tid] = ex[i] * inv;
}

extern "C" void kernel_launch(void* const* d_in, const int* in_sizes, int n_in,
                              void* d_out, int out_size, void* d_ws, size_t ws_size,
                              hipStream_t stream) {
    const float* dh   = (const float*)d_in[0];
    const float* enc  = (const float*)d_in[1];
    const int*   mask = (const int*)d_in[2];
    const float* Wa_w = (const float*)d_in[3];
    const float* Wa_b = (const float*)d_in[4];
    const float* Ua_w = (const float*)d_in[5];
    const float* Ua_b = (const float*)d_in[6];
    const float* Va_w = (const float*)d_in[7];
    const float* Va_b = (const float*)d_in[8];
    float* out = (float*)d_out;

    float* dec_proj = (float*)d_ws;                       // [B,H]    128 KB
    float* partials = dec_proj + BB*HH;                   // [M,16]   4 MB
    u16*   B_pre    = (u16*)(partials + (size_t)MT*16);   // frag-linear, 4 MB

    dec_proj_kernel<<<dim3(BB, 4), 256, 0, stream>>>(dh, Wa_w, Wa_b, Ua_b, dec_proj);
    transpose_convert_kernel<<<dim3(HH/64, HH/64), 256, 0, stream>>>(Ua_w, B_pre);
    gemm8_kernel<<<(MT/BM)*NCH, THREADS, 0, stream>>>(enc, B_pre, dec_proj, Va_w, partials);
    softmax_kernel<<<BB, 256, 0, stream>>>(partials, mask, Va_b, out);
}